// Round 9
// baseline (248.988 us; speedup 1.0000x reference)
//
#include <hip/hip_runtime.h>

// SGFormer encoder layer, MI355X gfx950.
// fp32 I/O per reference dtypes; bf16 MFMA internally.
// R2: CSR+gather scatter-mean. R3/4: static-max flash attn, V^T, K-split.
// R5: SPLITS=4, merged LQKV gemm. R8: glls+XOR-swizzle staging.
// R12: gemm_bt BK=128. R14: swapped QK^T + in-register P. R15: gather
// 4-deep pipeline; vtrans LDS transpose. R16: head=XCD mapping.
// R20: single-barrier dbuf. R21: lsum via ones-MFMA (VALU 41->39, neutral ->
//      attn is LATENCY-bound; micro-opts exhausted at this decomposition).
// R22: CSR chain pipelined one dispatch earlier:
//      memset(deg) -> hist@D1 (needs only ei) -> scan@D2 (1 blk) ->
//      fill@D3 -> GATHER rides D4 as attn z-slices (backfills attn's tail;
//      attn is <40% on all pipes -> ideal co-tenant) -> D5 = combine only.
//      Every producer in a strictly earlier dispatch; no ordering assumptions.

#define N_NODES 4096
#define C_DIM   512
#define H_HEADS 8
#define D_HEAD  64
#define E_EDGES 131072

typedef unsigned short u16;
typedef unsigned int   u32;
typedef u16   u16x8  __attribute__((ext_vector_type(8)));
typedef __bf16 bf16x8 __attribute__((ext_vector_type(8)));
typedef float  f32x4  __attribute__((ext_vector_type(4)));
typedef u32    u32x4  __attribute__((ext_vector_type(4)));

__device__ __forceinline__ float b2f(u16 u) {
  unsigned int i = ((unsigned int)u) << 16;
  return __builtin_bit_cast(float, i);
}
__device__ __forceinline__ u16 f2b(float f) {
  unsigned int i = __builtin_bit_cast(unsigned int, f);
  i += 0x7fffu + ((i >> 16) & 1u);   // RNE
  return (u16)(i >> 16);
}
// pack two f32 -> one u32 of 2 bf16 (no builtin on gfx950; inline asm)
__device__ __forceinline__ u32 cvtpk(float lo, float hi) {
  u32 r;
  asm("v_cvt_pk_bf16_f32 %0, %1, %2" : "=v"(r) : "v"(lo), "v"(hi));
  return r;
}
// gfx950 lane-group swaps (see R14 derivation).
__device__ __forceinline__ void pl32swap(u32& x, u32& y) {
  asm("v_permlane32_swap_b32 %0, %1" : "+v"(x), "+v"(y));
}
__device__ __forceinline__ void pl16swap(u32& x, u32& y) {
  asm("v_permlane16_swap_b32 %0, %1" : "+v"(x), "+v"(y));
}
// async global->LDS, 16B per lane; LDS dest = wave-uniform base + lane*16
__device__ __forceinline__ void glds16(const u16* g, u16* l) {
  __builtin_amdgcn_global_load_lds(
      (const __attribute__((address_space(1))) void*)g,
      (__attribute__((address_space(3))) void*)l, 16, 0, 0);
}

// ---------------- fp32 -> bf16 batched convert (+ hist slice t==7) ---------
struct CvtArgs {
  const float* src[7];
  u16* dst[7];
  int n[7];
  int* deg;
  const int* ei;
};

__global__ __launch_bounds__(256) void cvt_multi(CvtArgs a) {
  const int t = blockIdx.y;
  if (t == 7) {                       // degree histogram (deg zeroed by memset)
    if (blockIdx.x < 512) {           // 512 blocks x 256 thr = 131072 edges
      const int e = blockIdx.x * 256 + threadIdx.x;
      atomicAdd(&a.deg[a.ei[E_EDGES + e]], 1);
    }
    return;
  }
  const int i = (blockIdx.x * 256 + threadIdx.x) * 8;
  if (i >= a.n[t]) return;
  const float* s = a.src[t] + i;
  f32x4 v0 = *(const f32x4*)s;
  f32x4 v1 = *(const f32x4*)(s + 4);
  u16x8 o;
  o[0]=f2b(v0[0]); o[1]=f2b(v0[1]); o[2]=f2b(v0[2]); o[3]=f2b(v0[3]);
  o[4]=f2b(v1[0]); o[5]=f2b(v1[1]); o[6]=f2b(v1[2]); o[7]=f2b(v1[3]);
  *(u16x8*)(a.dst[t] + i) = o;
}

// ---------------- 64x64 tile GEMM, BK=128: out = A * W^T + bias -------------
// EPI: 1 = f32 out, 2 = gelu -> bf16, 3 = 0.5*local+0.5*v -> bf16
template<int EPI>
__global__ __launch_bounds__(256) void gemm_bt(
    const u16* __restrict__ A, const u16* __restrict__ W,
    const float* __restrict__ bias, void* __restrict__ outp,
    int M, int Nout, int K,
    const float* __restrict__ mloc)
{
  const int tid  = threadIdx.x;
  const int lane = tid & 63, wave = tid >> 6;
  const int quad = lane >> 4, l16 = lane & 15;
  const int wm = wave >> 1, wn = wave & 1;   // 2x2 wave grid, 32x32 per wave
  const int bm = blockIdx.x, bnb = blockIdx.y;

  __shared__ __align__(16) u16 As[64][128];   // BK=128, 32KB total
  __shared__ __align__(16) u16 Ws[64][128];

  f32x4 acc[2][2] = {};

  const int lr4 = lane >> 4, gs = lane & 15;
  const int g8e = (gs ^ lr4) * 8;         // c even: row&7 == lr4
  const int g8o = (gs ^ (4 + lr4)) * 8;   // c odd:  row&7 == 4+lr4
  const u16* aw[8];
#pragma unroll
  for (int c = 0; c < 4; ++c) {
    const int g8 = (c & 1) ? g8o : g8e;
    aw[c]     = A + (size_t)(bm  * 64 + wave * 16 + c * 4 + lr4) * K + g8;
    aw[4 + c] = W + (size_t)(bnb * 64 + wave * 16 + c * 4 + lr4) * K + g8;
  }

  for (int k0 = 0; k0 < K; k0 += 128) {
    __syncthreads();
#pragma unroll
    for (int c = 0; c < 4; ++c) {
      glds16(aw[c] + k0,     &As[wave * 16 + c * 4][0]);
      glds16(aw[4 + c] + k0, &Ws[wave * 16 + c * 4][0]);
    }
    __syncthreads();
#pragma unroll
    for (int ks = 0; ks < 4; ++ks) {
      const int slot = ((ks * 4 + quad) ^ (l16 & 7)) * 8;
      bf16x8 af[2], bf[2];
      af[0] = *(const bf16x8*)&As[wm * 32 +      l16][slot];
      af[1] = *(const bf16x8*)&As[wm * 32 + 16 + l16][slot];
      bf[0] = *(const bf16x8*)&Ws[wn * 32 +      l16][slot];
      bf[1] = *(const bf16x8*)&Ws[wn * 32 + 16 + l16][slot];
#pragma unroll
      for (int i = 0; i < 2; ++i)
#pragma unroll
        for (int j = 0; j < 2; ++j)
          acc[i][j] = __builtin_amdgcn_mfma_f32_16x16x32_bf16(af[i], bf[j], acc[i][j], 0, 0, 0);
    }
  }

#pragma unroll
  for (int i = 0; i < 2; ++i)
#pragma unroll
    for (int j = 0; j < 2; ++j) {
      const int col = bnb * 64 + wn * 32 + j * 16 + l16;
      const float bias_v = bias[col];
#pragma unroll
      for (int r = 0; r < 4; ++r) {
        const int row = bm * 64 + wm * 32 + i * 16 + quad * 4 + r;
        float v = acc[i][j][r] + bias_v;
        const size_t o = (size_t)row * Nout + col;
        if constexpr (EPI == 1) {
          ((float*)outp)[o] = v;
        } else if constexpr (EPI == 2) {
          float gl = 0.5f * v * (1.0f + erff(v * 0.70710678118654752f));
          ((u16*)outp)[o] = f2b(gl);
        } else {
          ((u16*)outp)[o] = f2b(0.5f * mloc[o] + 0.5f * v);
        }
      }
    }
}

// ---------------- 128x128 tile GEMM (glls, BK=64) + scan slice (y==16) ------
__global__ __launch_bounds__(256) void gemm128(
    const u16* __restrict__ A, const u16* __restrict__ W,
    const float* __restrict__ bias0, const float* __restrict__ bias1,
    u16* __restrict__ out0, u16* __restrict__ out1,
    int M, int Nout, int K,
    const int* __restrict__ deg, int* __restrict__ off, int* __restrict__ cursor)
{
  const int tid  = threadIdx.x;
  if (blockIdx.y == 16) {             // exclusive scan of 4096 degrees (1 blk)
    if (blockIdx.x != 0) return;
    __shared__ int part[256];
    const int t = tid;
    int v[16];
    int s = 0;
#pragma unroll
    for (int i = 0; i < 16; ++i) { v[i] = deg[t * 16 + i]; s += v[i]; }
    part[t] = s;
    __syncthreads();
    for (int d = 1; d < 256; d <<= 1) {
      int val = (t >= d) ? part[t - d] : 0;
      __syncthreads();
      if (t >= d) part[t] += val;
      __syncthreads();
    }
    int prefix = (t == 0) ? 0 : part[t - 1];
#pragma unroll
    for (int i = 0; i < 16; ++i) {
      off[t * 16 + i] = prefix;
      cursor[t * 16 + i] = prefix;
      prefix += v[i];
    }
    if (t == 255) off[4096] = prefix;
    return;
  }
  const int lane = tid & 63, wave = tid >> 6;
  const int quad = lane >> 4, l16 = lane & 15;
  const int wm = wave >> 1, wn = wave & 1;   // 2x2 wave grid, 64x64 per wave
  const int bm = blockIdx.x, bnb = blockIdx.y;

  __shared__ __align__(16) u16 As[128][64];
  __shared__ __align__(16) u16 Ws[128][64];

  f32x4 acc[4][4] = {};

  const int lr = lane >> 3, gs = lane & 7;
  const int g8 = (gs ^ lr) * 8;
  const u16* ab = A + (size_t)(bm  * 128 + wave * 32 + lr) * K + g8;
  const u16* wb = W + (size_t)(bnb * 128 + wave * 32 + lr) * K + g8;

  for (int k0 = 0; k0 < K; k0 += 64) {
    __syncthreads();
#pragma unroll
    for (int c = 0; c < 4; ++c) {
      glds16(ab + (size_t)(c * 8) * K + k0, &As[wave * 32 + c * 8][0]);
      glds16(wb + (size_t)(c * 8) * K + k0, &Ws[wave * 32 + c * 8][0]);
    }
    __syncthreads();
#pragma unroll
    for (int ks = 0; ks < 2; ++ks) {
      const int slot = ((ks * 4 + quad) ^ (l16 & 7)) * 8;
      bf16x8 af[4], bf[4];
#pragma unroll
      for (int am = 0; am < 4; ++am)
        af[am] = *(const bf16x8*)&As[wm * 64 + am * 16 + l16][slot];
#pragma unroll
      for (int bn = 0; bn < 4; ++bn)
        bf[bn] = *(const bf16x8*)&Ws[wn * 64 + bn * 16 + l16][slot];
#pragma unroll
      for (int am = 0; am < 4; ++am)
#pragma unroll
        for (int bn = 0; bn < 4; ++bn)
          acc[am][bn] = __builtin_amdgcn_mfma_f32_16x16x32_bf16(af[am], bf[bn], acc[am][bn], 0, 0, 0);
    }
  }

#pragma unroll
  for (int am = 0; am < 4; ++am)
#pragma unroll
    for (int bn = 0; bn < 4; ++bn) {
      const int col = bnb * 128 + wn * 64 + bn * 16 + l16;
      const float bias_v = (col < 512) ? bias0[col] : bias1[col - 512];
#pragma unroll
      for (int r = 0; r < 4; ++r) {
        const int row = bm * 128 + wm * 64 + am * 16 + quad * 4 + r;
        float v = acc[am][bn][r] + bias_v;
        if (col < 512) out0[(size_t)row * 512 + col] = f2b(v);
        else           out1[(size_t)row * 1536 + (col - 512)] = f2b(v);
      }
    }
}

// ---------------- V transpose (bx<512) + CSR fill (bx>=512), one dispatch ---
__global__ __launch_bounds__(256) void vtrans_fill(
    const u16* __restrict__ qkv, u16* __restrict__ vt,
    const int* __restrict__ ei, int* __restrict__ cursor, int* __restrict__ csr)
{
  const int tid = threadIdx.x;
  if (blockIdx.x >= 512) {            // CSR fill: 256 blocks, 2 edges/thread
    const int sblk = blockIdx.x - 512;
#pragma unroll
    for (int i = 0; i < 2; ++i) {
      const int e = sblk * 512 + i * 256 + tid;
      const int s = ei[e];
      const int d = ei[E_EDGES + e];
      const int p = atomicAdd(&cursor[d], 1);
      csr[p] = s;
    }
    return;
  }
  // vtrans: vt[h][d][m] = V[m][h][d], one 64m x 64d head-tile per block
  __shared__ __align__(16) u16 T[64][64];
  const int h = blockIdx.x >> 6, mt = blockIdx.x & 63;
  const int m0 = mt * 64;
  const int c  = tid & 7;            // d-chunk (8 u16 = 16B)
  const int mr = tid >> 3;           // 0..31
#pragma unroll
  for (int half = 0; half < 2; ++half) {
    const int m = mr + half * 32;
    const u16x8 v = *(const u16x8*)(qkv + (size_t)(m0 + m) * 1536 + 1024 + h * 64 + c * 8);
    // store element (m,d) at column-chunk (d>>3) ^ (m>>3): bank-clean both ways
    *(u16x8*)&T[m][((c ^ (m >> 3)) * 8)] = v;
  }
  __syncthreads();
#pragma unroll
  for (int half = 0; half < 2; ++half) {
    const int q = tid + half * 256;
    const int d = q >> 3, mc = q & 7;
    u16x8 w;
#pragma unroll
    for (int e = 0; e < 8; ++e)
      w[e] = T[mc * 8 + e][(((d >> 3) ^ mc) * 8) + (d & 7)];
    *(u16x8*)(vt + (size_t)(h * 64 + d) * N_NODES + m0 + mc * 8) = w;
  }
}

// ---------------- flash attention (+ gather slices at z>=SPLITS) ------------
// Swapped QK^T + in-register P (R14); head=XCD mapping (R16); single-barrier
// dbuf (R20); lsum via ones-MFMA (R21). R22: the scatter-mean GATHER rides
// this dispatch as z in [SPLITS, SPLITS+4) — 1024 blocks that backfill CUs
// during the attn tail (csr/off complete since D3/D2).
template<int SPLITS>
__global__ __launch_bounds__(256) void attn_kernel(
    const u16* __restrict__ qkv, const u16* __restrict__ vt,
    u16* __restrict__ opart, float* __restrict__ lpart,
    const int* __restrict__ off, const int* __restrict__ csr,
    const u16* __restrict__ lh, float* __restrict__ lo)
{
  const int tid = threadIdx.x, wave = tid >> 6, lane = tid & 63;
  const int split = blockIdx.z;
  if (split >= SPLITS) {              // gather: one wave per dst node
    const int gblk = (split - SPLITS) * 256 + blockIdx.y * 32 + blockIdx.x;
    const int n = gblk * 4 + wave;
    const int j0 = off[n], j1 = off[n + 1];
    float acc[8] = {};
    int j = j0;
    for (; j + 4 <= j1; j += 4) {     // 4 independent row loads in flight
      const int s0 = csr[j], s1 = csr[j + 1], s2 = csr[j + 2], s3 = csr[j + 3];
      const u16x8 v0 = *(const u16x8*)(lh + (size_t)s0 * C_DIM + lane * 8);
      const u16x8 v1 = *(const u16x8*)(lh + (size_t)s1 * C_DIM + lane * 8);
      const u16x8 v2 = *(const u16x8*)(lh + (size_t)s2 * C_DIM + lane * 8);
      const u16x8 v3 = *(const u16x8*)(lh + (size_t)s3 * C_DIM + lane * 8);
#pragma unroll
      for (int i = 0; i < 8; ++i)
        acc[i] += (b2f(v0[i]) + b2f(v1[i])) + (b2f(v2[i]) + b2f(v3[i]));
    }
    for (; j < j1; ++j) {
      const int s = csr[j];
      const u16x8 v = *(const u16x8*)(lh + (size_t)s * C_DIM + lane * 8);
#pragma unroll
      for (int i = 0; i < 8; ++i) acc[i] += b2f(v[i]);
    }
    const float inv = 1.0f / fmaxf((float)(j1 - j0), 1.0f);
    f32x4 o0, o1;
#pragma unroll
    for (int i = 0; i < 4; ++i) { o0[i] = acc[i] * inv; o1[i] = acc[4 + i] * inv; }
    float* op = lo + (size_t)n * C_DIM + lane * 8;
    *(f32x4*)op = o0;
    *(f32x4*)(op + 4) = o1;
    return;
  }
  const int quad = lane >> 4, l16 = lane & 15;
  // head = linear_block_id % 8 (= XCD on MI355X round-robin dispatch)
  const int h = blockIdx.x & 7;
  const int tile = (blockIdx.x >> 3) + (blockIdx.y << 2);

  __shared__ __align__(16) u16 Ks[2][64][64];    // K tiles, XOR-swizzled, dbuf
  __shared__ __align__(16) u16 Vts[2][64][64];   // V^T tiles, XOR-swizzled, dbuf

  const float QSCALE = 0.18033688011112042f;  // log2(e)/8
  bf16x8 aq[2][2];   // Q[l16][quad*8..+7]: B-operand for K*Q^T
#pragma unroll
  for (int mb = 0; mb < 2; ++mb) {
    const int qrow = tile * 128 + wave * 32 + mb * 16 + l16;
    const u16* qp = qkv + (size_t)qrow * 1536 + h * 64 + quad * 8;
    u16x8 q0 = *(const u16x8*)qp;
    u16x8 q1 = *(const u16x8*)(qp + 32);
    u16x8 s0, s1;
#pragma unroll
    for (int i = 0; i < 8; ++i) {
      s0[i] = f2b(b2f(q0[i]) * QSCALE);
      s1[i] = f2b(b2f(q1[i]) * QSCALE);
    }
    aq[mb][0] = __builtin_bit_cast(bf16x8, s0);
    aq[mb][1] = __builtin_bit_cast(bf16x8, s1);
  }

  // all-ones B-fragment for P*1 row-sums on the matrix pipe
  u16x8 ones_u;
#pragma unroll
  for (int i = 0; i < 8; ++i) ones_u[i] = 0x3F80;
  const bf16x8 vone = __builtin_bit_cast(bf16x8, ones_u);

  f32x4 O[2][4] = {};
  f32x4 lacc[2] = {};   // D[q][*] = sum_k P[q][k] (cols identical)

  const int lr = lane >> 3, gs = lane & 7;
  const int g8 = (gs ^ lr) * 8;
  const int R0 = wave * 16 + lr;

  const u16* kp = qkv + (size_t)R0 * 1536 + 512 + h * 64 + g8;
  const u16* vp = vt + (size_t)(h * 64 + R0) * N_NODES + g8;

  const int mt0 = split * (64 / SPLITS), mt1 = (split + 1) * (64 / SPLITS);

  {   // prologue: stage first tile into buffer 0
    const size_t ko = (size_t)mt0 * 64 * 1536;
    glds16(kp + ko,            &Ks[0][wave * 16][0]);
    glds16(kp + ko + 8 * 1536, &Ks[0][wave * 16 + 8][0]);
    glds16(vp + mt0 * 64,               &Vts[0][wave * 16][0]);
    glds16(vp + mt0 * 64 + 8 * N_NODES, &Vts[0][wave * 16 + 8][0]);
  }

  for (int mt = mt0; mt < mt1; ++mt) {
    const int cur = (mt - mt0) & 1;
    // my stage(t) loads landed (issued after the previous barrier, they had a
    // full compute phase to complete)
    asm volatile("s_waitcnt vmcnt(0)" ::: "memory");
    __builtin_amdgcn_s_barrier();     // all waves' stage(t) landed; buf^1 free
    __builtin_amdgcn_sched_barrier(0);
    if (mt + 1 < mt1) {               // restage buf^1; lands during compute
      const size_t ko = (size_t)(mt + 1) * 64 * 1536;
      glds16(kp + ko,            &Ks[cur ^ 1][wave * 16][0]);
      glds16(kp + ko + 8 * 1536, &Ks[cur ^ 1][wave * 16 + 8][0]);
      glds16(vp + (mt + 1) * 64,               &Vts[cur ^ 1][wave * 16][0]);
      glds16(vp + (mt + 1) * 64 + 8 * N_NODES, &Vts[cur ^ 1][wave * 16 + 8][0]);
    }

    // S^T = K (cQ)^T : D[row=m_local][col=q]
    f32x4 st[2][4] = {};
    __builtin_amdgcn_s_setprio(1);
#pragma unroll
    for (int ks = 0; ks < 2; ++ks) {
      const int slot = ((ks * 4 + quad) ^ (l16 & 7)) * 8;
      bf16x8 af[4];
#pragma unroll
      for (int jn = 0; jn < 4; ++jn)
        af[jn] = *(const bf16x8*)&Ks[cur][jn * 16 + l16][slot];
#pragma unroll
      for (int mb = 0; mb < 2; ++mb)
#pragma unroll
        for (int jn = 0; jn < 4; ++jn)
          st[mb][jn] = __builtin_amdgcn_mfma_f32_16x16x32_bf16(af[jn], aq[mb][ks], st[mb][jn], 0, 0, 0);
    }
    __builtin_amdgcn_s_setprio(0);

    // p = exp2(st): lane (q=l16, quad) holds P[q][m = jn*16 + quad*4 + r].
    // Pack pairs, then 2-stage swap butterfly -> PV A-frag (R14 mapping):
    //   A[ks][c]@quad t  <-  pk[jn][i]@quad qs,
    //   ks=jn>>1, c=2*(qs&1)+i, t=2*(jn&1)+(qs>>1)   (bijective)
    bf16x8 pa[2][2];
#pragma unroll
    for (int mb = 0; mb < 2; ++mb) {
      u32 pk[4][2];
#pragma unroll
      for (int jn = 0; jn < 4; ++jn) {
        float p0 = __builtin_amdgcn_exp2f(st[mb][jn][0]);
        float p1 = __builtin_amdgcn_exp2f(st[mb][jn][1]);
        float p2 = __builtin_amdgcn_exp2f(st[mb][jn][2]);
        float p3 = __builtin_amdgcn_exp2f(st[mb][jn][3]);
        pk[jn][0] = cvtpk(p0, p1);
        pk[jn][1] = cvtpk(p2, p3);
      }
#pragma unroll
      for (int ks = 0; ks < 2; ++ks) {
        u32 x0 = pk[2 * ks][0], y0 = pk[2 * ks + 1][0];
        u32 x1 = pk[2 * ks][1], y1 = pk[2 * ks + 1][1];
        pl32swap(x0, y0); pl16swap(x0, y0);
        pl32swap(x1, y1); pl16swap(x1, y1);
        u32x4 av;
        av[0] = x0; av[1] = x1; av[2] = y0; av[3] = y1;
        pa[mb][ks] = __builtin_bit_cast(bf16x8, av);
      }
    }

    // O += P V ; lacc += P * 1 (row-sum on the matrix pipe)
    __builtin_amdgcn_s_setprio(1);
#pragma unroll
    for (int ks = 0; ks < 2; ++ks) {
      const int slot = ((ks * 4 + quad) ^ (l16 & 7)) * 8;
      bf16x8 bv[4];
#pragma unroll
      for (int jd = 0; jd < 4; ++jd)
        bv[jd] = *(const bf16x8*)&Vts[cur][jd * 16 + l16][slot];
#pragma unroll
      for (int mb = 0; mb < 2; ++mb) {
#pragma unroll
        for (int jd = 0; jd < 4; ++jd)
          O[mb][jd] = __builtin_amdgcn_mfma_f32_16x16x32_bf16(pa[mb][ks], bv[jd], O[mb][jd], 0, 0, 0);
        lacc[mb] = __builtin_amdgcn_mfma_f32_16x16x32_bf16(pa[mb][ks], vone, lacc[mb], 0, 0, 0);
      }
    }
    __builtin_amdgcn_s_setprio(0);
    // no bottom barrier: next iteration's vmcnt(0)+barrier covers both hazards
  }

  // write unnormalized partials (bf16) + row sums (lacc cols identical)
#pragma unroll
  for (int mb = 0; mb < 2; ++mb) {
#pragma unroll
    for (int r = 0; r < 4; ++r) {
      const int row = tile * 128 + wave * 32 + mb * 16 + quad * 4 + r;
      u16* orow = opart + ((size_t)split * N_NODES + row) * C_DIM + h * 64;
#pragma unroll
      for (int jd = 0; jd < 4; ++jd)
        orow[jd * 16 + l16] = f2b(O[mb][jd][r]);
      if (l16 == 0)
        lpart[((size_t)split * N_NODES + row) * H_HEADS + h] = lacc[mb][r];
    }
  }
}

// ---------------- combine split partials (1024 blocks) ----------------------
template<int SPLITS>
__global__ __launch_bounds__(256) void combine_kernel(
    const u16* __restrict__ opart, const float* __restrict__ lpart,
    u16* __restrict__ ctx)
{
  const size_t base = (size_t)(blockIdx.x * 256 + threadIdx.x) * 8;
  const int row = (int)(base >> 9);
  const int h = (int)((base & 511) >> 6);
  float l = 0.0f;
#pragma unroll
  for (int s = 0; s < SPLITS; ++s)
    l += lpart[(size_t)s * N_NODES * H_HEADS + (size_t)row * H_HEADS + h];
  const float inv = 1.0f / l;
  float o[8] = {};
#pragma unroll
  for (int s = 0; s < SPLITS; ++s) {
    const u16x8 p = *(const u16x8*)(opart + (size_t)s * N_NODES * C_DIM + base);
#pragma unroll
    for (int i = 0; i < 8; ++i) o[i] += b2f(p[i]);
  }
  u16x8 ob;
#pragma unroll
  for (int i = 0; i < 8; ++i) ob[i] = f2b(o[i] * inv);
  *(u16x8*)(ctx + base) = ob;
}

// ---------------- LayerNorms (one wave per row) ----------------
__global__ __launch_bounds__(256) void ln1_kernel(
    const float* __restrict__ x, const float* __restrict__ pr,
    const float* __restrict__ g, const float* __restrict__ b,
    u16* __restrict__ hb, float* __restrict__ hf)
{
  const int wave = threadIdx.x >> 6, lane = threadIdx.x & 63;
  const int row = blockIdx.x * 4 + wave;
  const int c0 = lane * 8;
  const size_t base = (size_t)row * C_DIM + c0;
  f32x4 x0 = *(const f32x4*)(x + base);
  f32x4 x1 = *(const f32x4*)(x + base + 4);
  f32x4 p0 = *(const f32x4*)(pr + base);
  f32x4 p1 = *(const f32x4*)(pr + base + 4);
  float v[8];
#pragma unroll
  for (int i = 0; i < 4; ++i) { v[i] = x0[i] + p0[i]; v[4 + i] = x1[i] + p1[i]; }
  float sum = 0, sq = 0;
#pragma unroll
  for (int i = 0; i < 8; ++i) { sum += v[i]; sq += v[i] * v[i]; }
  for (int off = 1; off < 64; off <<= 1) { sum += __shfl_xor(sum, off); sq += __shfl_xor(sq, off); }
  const float mean = sum * (1.0f / C_DIM);
  const float var  = sq * (1.0f / C_DIM) - mean * mean;
  const float rstd = rsqrtf(var + 1e-5f);
  f32x4 g0 = *(const f32x4*)(g + c0), g1 = *(const f32x4*)(g + c0 + 4);
  f32x4 b0 = *(const f32x4*)(b + c0), b1 = *(const f32x4*)(b + c0 + 4);
  u16x8 ob; f32x4 h0, h1;
#pragma unroll
  for (int i = 0; i < 4; ++i) {
    float hv0 = (v[i]     - mean) * rstd * g0[i] + b0[i];
    float hv1 = (v[4 + i] - mean) * rstd * g1[i] + b1[i];
    h0[i] = hv0; h1[i] = hv1;
    ob[i] = f2b(hv0); ob[4 + i] = f2b(hv1);
  }
  *(u16x8*)(hb + base) = ob;
  *(f32x4*)(hf + base) = h0;
  *(f32x4*)(hf + base + 4) = h1;
}

__global__ __launch_bounds__(256) void ln2_kernel(
    const float* __restrict__ a, const float* __restrict__ c,
    const float* __restrict__ g, const float* __restrict__ b,
    float* __restrict__ out)
{
  const int wave = threadIdx.x >> 6, lane = threadIdx.x & 63;
  const int row = blockIdx.x * 4 + wave;
  const int c0 = lane * 8;
  const size_t base = (size_t)row * C_DIM + c0;
  f32x4 a0 = *(const f32x4*)(a + base), a1 = *(const f32x4*)(a + base + 4);
  f32x4 c0v = *(const f32x4*)(c + base), c1v = *(const f32x4*)(c + base + 4);
  float v[8];
#pragma unroll
  for (int i = 0; i < 4; ++i) { v[i] = a0[i] + c0v[i]; v[4 + i] = a1[i] + c1v[i]; }
  float sum = 0, sq = 0;
#pragma unroll
  for (int i = 0; i < 8; ++i) { sum += v[i]; sq += v[i] * v[i]; }
  for (int off = 1; off < 64; off <<= 1) { sum += __shfl_xor(sum, off); sq += __shfl_xor(sq, off); }
  const float mean = sum * (1.0f / C_DIM);
  const float var  = sq * (1.0f / C_DIM) - mean * mean;
  const float rstd = rsqrtf(var + 1e-5f);
  f32x4 g0 = *(const f32x4*)(g + c0), g1 = *(const f32x4*)(g + c0 + 4);
  f32x4 b0 = *(const f32x4*)(b + c0), b1 = *(const f32x4*)(b + c0 + 4);
  f32x4 h0, h1;
#pragma unroll
  for (int i = 0; i < 4; ++i) {
    h0[i] = (v[i]     - mean) * rstd * g0[i] + b0[i];
    h1[i] = (v[4 + i] - mean) * rstd * g1[i] + b1[i];
  }
  *(f32x4*)(out + base) = h0;
  *(f32x4*)(out + base + 4) = h1;
}

// ---------------- launch ----------------
extern "C" void kernel_launch(void* const* d_in, const int* in_sizes, int n_in,
                              void* d_out, int out_size, void* d_ws, size_t ws_size,
                              hipStream_t stream) {
  const float* x          = (const float*)d_in[0];
  const int*   ei         = (const int*)d_in[1];
  const float* local_w    = (const float*)d_in[2];
  const float* local_b    = (const float*)d_in[3];
  const float* in_proj_w  = (const float*)d_in[4];
  const float* in_proj_b  = (const float*)d_in[5];
  const float* attn_out_w = (const float*)d_in[6];
  const float* attn_out_b = (const float*)d_in[7];
  const float* output_w   = (const float*)d_in[8];
  const float* output_b   = (const float*)d_in[9];
  const float* n1g = (const float*)d_in[10];
  const float* n1b = (const float*)d_in[11];
  const float* n2g = (const float*)d_in[12];
  const float* n2b = (const float*)d_in[13];
  const float* ffn_w1 = (const float*)d_in[14];
  const float* ffn_b1 = (const float*)d_in[15];
  const float* ffn_w2 = (const float*)d_in[16];
  const float* ffn_b2 = (const float*)d_in[17];
  float* out = (float*)d_out;

  char* ws = (char*)d_ws;
  size_t o = 0;
  float* local_out = (float*)(ws + o); o += (size_t)N_NODES * C_DIM * 4;  // 8 MB
  int* deg    = (int*)(ws + o); o += (N_NODES) * 4;
  int* off    = (int*)(ws + o); o += (N_NODES + 16) * 4;
  int* cursor = (int*)(ws + o); o += (N_NODES) * 4;
  int* csr    = (int*)(ws + o); o += (size_t)E_EDGES * 4;
  u16* xb   = (u16*)(ws + o); o += (size_t)N_NODES * C_DIM * 2;           // 4 MB
  u16* wbLQ = (u16*)(ws + o); o += (size_t)4 * C_DIM * C_DIM * 2;         // 2 MB
  u16* wbA  = (u16*)(ws + o); o += (size_t)C_DIM * C_DIM * 2;
  u16* wbO  = (u16*)(ws + o); o += (size_t)C_DIM * C_DIM * 2;
  u16* wbF1 = (u16*)(ws + o); o += (size_t)2 * C_DIM * C_DIM * 2;
  u16* wbF2 = (u16*)(ws + o); o += (size_t)2 * C_DIM * C_DIM * 2;
  u16* local_h   = (u16*)(ws + o); o += (size_t)N_NODES * C_DIM * 2;
  u16* qkvb      = (u16*)(ws + o); o += (size_t)N_NODES * 3 * C_DIM * 2;  // 12 MB
  u16* ctxb      = (u16*)(ws + o); o += (size_t)N_NODES * C_DIM * 2;
  u16* mixed     = (u16*)(ws + o); o += (size_t)N_NODES * C_DIM * 2;
  u16* hidden_bf = (u16*)(ws + o); o += (size_t)N_NODES * C_DIM * 2;      // 4 MB
  float* hidden_f = (float*)(ws + o); o += (size_t)N_NODES * C_DIM * 4;   // 8 MB
  u16* ff1       = (u16*)(ws + o); o += (size_t)N_NODES * 2 * C_DIM * 2;  // 8 MB
  // aliases (dead ranges reused):
  float* proj  = (float*)qkvb;       // qkv dead after attn; proj 8 MB <= 12 MB
  float* ff2   = (float*)local_out;  // local_out dead after mix-epilogue gemm
  u16*   vt    = xb;                 // xb dead after LQKV gemm; 4 MB
  // SPLITS=4 bf16 partials (16.25 MB) past static region if workspace allows
  u16* opart4 = (u16*)(ws + o);
  float* lpart4 = (float*)(ws + o + (size_t)4 * N_NODES * C_DIM * 2);
  const size_t need4 = o + (size_t)4 * N_NODES * C_DIM * 2 + (size_t)4 * N_NODES * H_HEADS * 4;
  const bool use4 = (ws_size >= need4);
  // SPLITS=2 fallback: inside hidden_bf..ff1 region (8.25 MB <= 20 MB)
  u16* opart2 = (u16*)hidden_bf;
  float* lpart2 = (float*)(opart2 + (size_t)2 * N_NODES * C_DIM);

  // D0: zero degree counters (ws is poisoned); capture-legal async memset
  hipMemsetAsync(deg, 0, N_NODES * sizeof(int), stream);

  // D1: fp32 -> bf16 conversions + degree histogram (slice t==7)
  CvtArgs ca;
  ca.src[0] = x;          ca.dst[0] = xb;   ca.n[0] = N_NODES * C_DIM;
  ca.src[1] = local_w;    ca.dst[1] = wbLQ;                  ca.n[1] = C_DIM * C_DIM;
  ca.src[2] = in_proj_w;  ca.dst[2] = wbLQ + C_DIM * C_DIM;  ca.n[2] = 3 * C_DIM * C_DIM;
  ca.src[3] = attn_out_w; ca.dst[3] = wbA;  ca.n[3] = C_DIM * C_DIM;
  ca.src[4] = output_w;   ca.dst[4] = wbO;  ca.n[4] = C_DIM * C_DIM;
  ca.src[5] = ffn_w1;     ca.dst[5] = wbF1; ca.n[5] = 2 * C_DIM * C_DIM;
  ca.src[6] = ffn_w2;     ca.dst[6] = wbF2; ca.n[6] = 2 * C_DIM * C_DIM;
  ca.deg = deg;
  ca.ei = ei;
  cvt_multi<<<dim3(N_NODES * C_DIM / 2048, 8), 256, 0, stream>>>(ca);

  // D2: merged local+qkv GEMM + degree scan (y==16, x==0)
  gemm128<<<dim3(32, 17), 256, 0, stream>>>(xb, wbLQ, local_b, in_proj_b,
      local_h, qkvb, N_NODES, 4 * C_DIM, C_DIM, deg, off, cursor);

  // D3: V transpose (bx<512) + CSR fill (bx>=512); xb dead after D2
  vtrans_fill<<<768, 256, 0, stream>>>(qkvb, vt, ei, cursor, csr);

  // D4: attention + gather slices (z in [SPLITS, SPLITS+4)); D5: combine
  if (use4) {
    attn_kernel<4><<<dim3(32, 8, 8), 256, 0, stream>>>(qkvb, vt, opart4, lpart4,
        off, csr, local_h, local_out);
    combine_kernel<4><<<1024, 256, 0, stream>>>(opart4, lpart4, ctxb);
  } else {
    attn_kernel<2><<<dim3(32, 8, 6), 256, 0, stream>>>(qkvb, vt, opart2, lpart2,
        off, csr, local_h, local_out);
    combine_kernel<2><<<1024, 256, 0, stream>>>(opart2, lpart2, ctxb);
  }

  // D6: mixed = 0.5*local_out + 0.5*(ctx @ attn_out_w^T + b)
  gemm_bt<3><<<dim3(64, 8), 256, 0, stream>>>(ctxb, wbA, attn_out_b, mixed,
      N_NODES, C_DIM, C_DIM, local_out);

  // D7: proj = mixed @ output_w^T + b ; D8: hidden = LN(x + proj)
  gemm_bt<1><<<dim3(64, 8), 256, 0, stream>>>(mixed, wbO, output_b, proj,
      N_NODES, C_DIM, C_DIM, nullptr);
  ln1_kernel<<<N_NODES / 4, 256, 0, stream>>>(x, proj, n1g, n1b, hidden_bf, hidden_f);

  // D9-D11: FFN + LN2
  gemm_bt<2><<<dim3(64, 16), 256, 0, stream>>>(hidden_bf, wbF1, ffn_b1, ff1,
      N_NODES, 2 * C_DIM, C_DIM, nullptr);
  gemm_bt<1><<<dim3(64, 8), 256, 0, stream>>>(ff1, wbF2, ffn_b2, ff2,
      N_NODES, C_DIM, 2 * C_DIM, nullptr);
  ln2_kernel<<<N_NODES / 4, 256, 0, stream>>>(hidden_f, ff2, n2g, n2b, out);
}

// Round 10
// 241.475 us; speedup vs baseline: 1.0311x; 1.0311x over previous
//
#include <hip/hip_runtime.h>

// SGFormer encoder layer, MI355X gfx950.
// fp32 I/O per reference dtypes; bf16 MFMA internally.
// R2: CSR+gather scatter-mean. R3/4: static-max flash attn, V^T, K-split.
// R5: merged LQKV gemm. R8: glls+XOR-swizzle staging. R12: gemm_bt BK=128.
// R14: swapped QK^T + in-register P. R15: gather 4-deep pipeline; vtrans
// LDS transpose. R16: head=XCD mapping. R20: single-barrier dbuf.
// R21: lsum via ones-MFMA. (R22 gather-under-attn REVERTED: old D5 already
// overlapped gather with combine; co-tenancy with latency-bound attn lost 5us.)
// R23: SPLITS=4 -> 5. attn is latency-bound (no pipe >40%, VALU removal
//      neutral); the untried lever is TLP. 32KB LDS x 5 = 160KB exactly ->
//      5 blocks/CU (was 4). Grid (32,8,6) keeps head=XCD (id%8 = x%8);
//      1280 blocks = exactly 5 per CU per XCD. Fallback 5->4->2 on ws_size.

#define N_NODES 4096
#define C_DIM   512
#define H_HEADS 8
#define D_HEAD  64
#define E_EDGES 131072

typedef unsigned short u16;
typedef unsigned int   u32;
typedef u16   u16x8  __attribute__((ext_vector_type(8)));
typedef __bf16 bf16x8 __attribute__((ext_vector_type(8)));
typedef float  f32x4  __attribute__((ext_vector_type(4)));
typedef u32    u32x4  __attribute__((ext_vector_type(4)));

__device__ __forceinline__ float b2f(u16 u) {
  unsigned int i = ((unsigned int)u) << 16;
  return __builtin_bit_cast(float, i);
}
__device__ __forceinline__ u16 f2b(float f) {
  unsigned int i = __builtin_bit_cast(unsigned int, f);
  i += 0x7fffu + ((i >> 16) & 1u);   // RNE
  return (u16)(i >> 16);
}
// pack two f32 -> one u32 of 2 bf16 (no builtin on gfx950; inline asm)
__device__ __forceinline__ u32 cvtpk(float lo, float hi) {
  u32 r;
  asm("v_cvt_pk_bf16_f32 %0, %1, %2" : "=v"(r) : "v"(lo), "v"(hi));
  return r;
}
// gfx950 lane-group swaps (see R14 derivation).
__device__ __forceinline__ void pl32swap(u32& x, u32& y) {
  asm("v_permlane32_swap_b32 %0, %1" : "+v"(x), "+v"(y));
}
__device__ __forceinline__ void pl16swap(u32& x, u32& y) {
  asm("v_permlane16_swap_b32 %0, %1" : "+v"(x), "+v"(y));
}
// async global->LDS, 16B per lane; LDS dest = wave-uniform base + lane*16
__device__ __forceinline__ void glds16(const u16* g, u16* l) {
  __builtin_amdgcn_global_load_lds(
      (const __attribute__((address_space(1))) void*)g,
      (__attribute__((address_space(3))) void*)l, 16, 0, 0);
}

// ---------------- fp32 -> bf16 batched convert (+ deg zero slice) ----------
struct CvtArgs {
  const float* src[7];
  u16* dst[7];
  int n[7];
  int* deg;
};

__global__ __launch_bounds__(256) void cvt_multi(CvtArgs a) {
  const int t = blockIdx.y;
  if (t == 7) {                       // zero degree counters (ws is poisoned)
    const int i = blockIdx.x * 256 + threadIdx.x;
    if (i < N_NODES) a.deg[i] = 0;
    return;
  }
  const int i = (blockIdx.x * 256 + threadIdx.x) * 8;
  if (i >= a.n[t]) return;
  const float* s = a.src[t] + i;
  f32x4 v0 = *(const f32x4*)s;
  f32x4 v1 = *(const f32x4*)(s + 4);
  u16x8 o;
  o[0]=f2b(v0[0]); o[1]=f2b(v0[1]); o[2]=f2b(v0[2]); o[3]=f2b(v0[3]);
  o[4]=f2b(v1[0]); o[5]=f2b(v1[1]); o[6]=f2b(v1[2]); o[7]=f2b(v1[3]);
  *(u16x8*)(a.dst[t] + i) = o;
}

// ---------------- 64x64 tile GEMM, BK=128: out = A * W^T + bias -------------
// EPI: 1 = f32 out, 2 = gelu -> bf16, 3 = 0.5*local+0.5*v -> bf16
template<int EPI>
__global__ __launch_bounds__(256) void gemm_bt(
    const u16* __restrict__ A, const u16* __restrict__ W,
    const float* __restrict__ bias, void* __restrict__ outp,
    int M, int Nout, int K,
    const float* __restrict__ mloc)
{
  const int tid  = threadIdx.x;
  const int lane = tid & 63, wave = tid >> 6;
  const int quad = lane >> 4, l16 = lane & 15;
  const int wm = wave >> 1, wn = wave & 1;   // 2x2 wave grid, 32x32 per wave
  const int bm = blockIdx.x, bnb = blockIdx.y;

  __shared__ __align__(16) u16 As[64][128];   // BK=128, 32KB total
  __shared__ __align__(16) u16 Ws[64][128];

  f32x4 acc[2][2] = {};

  const int lr4 = lane >> 4, gs = lane & 15;
  const int g8e = (gs ^ lr4) * 8;         // c even: row&7 == lr4
  const int g8o = (gs ^ (4 + lr4)) * 8;   // c odd:  row&7 == 4+lr4
  const u16* aw[8];
#pragma unroll
  for (int c = 0; c < 4; ++c) {
    const int g8 = (c & 1) ? g8o : g8e;
    aw[c]     = A + (size_t)(bm  * 64 + wave * 16 + c * 4 + lr4) * K + g8;
    aw[4 + c] = W + (size_t)(bnb * 64 + wave * 16 + c * 4 + lr4) * K + g8;
  }

  for (int k0 = 0; k0 < K; k0 += 128) {
    __syncthreads();
#pragma unroll
    for (int c = 0; c < 4; ++c) {
      glds16(aw[c] + k0,     &As[wave * 16 + c * 4][0]);
      glds16(aw[4 + c] + k0, &Ws[wave * 16 + c * 4][0]);
    }
    __syncthreads();
#pragma unroll
    for (int ks = 0; ks < 4; ++ks) {
      const int slot = ((ks * 4 + quad) ^ (l16 & 7)) * 8;
      bf16x8 af[2], bf[2];
      af[0] = *(const bf16x8*)&As[wm * 32 +      l16][slot];
      af[1] = *(const bf16x8*)&As[wm * 32 + 16 + l16][slot];
      bf[0] = *(const bf16x8*)&Ws[wn * 32 +      l16][slot];
      bf[1] = *(const bf16x8*)&Ws[wn * 32 + 16 + l16][slot];
#pragma unroll
      for (int i = 0; i < 2; ++i)
#pragma unroll
        for (int j = 0; j < 2; ++j)
          acc[i][j] = __builtin_amdgcn_mfma_f32_16x16x32_bf16(af[i], bf[j], acc[i][j], 0, 0, 0);
    }
  }

#pragma unroll
  for (int i = 0; i < 2; ++i)
#pragma unroll
    for (int j = 0; j < 2; ++j) {
      const int col = bnb * 64 + wn * 32 + j * 16 + l16;
      const float bias_v = bias[col];
#pragma unroll
      for (int r = 0; r < 4; ++r) {
        const int row = bm * 64 + wm * 32 + i * 16 + quad * 4 + r;
        float v = acc[i][j][r] + bias_v;
        const size_t o = (size_t)row * Nout + col;
        if constexpr (EPI == 1) {
          ((float*)outp)[o] = v;
        } else if constexpr (EPI == 2) {
          float gl = 0.5f * v * (1.0f + erff(v * 0.70710678118654752f));
          ((u16*)outp)[o] = f2b(gl);
        } else {
          ((u16*)outp)[o] = f2b(0.5f * mloc[o] + 0.5f * v);
        }
      }
    }
}

// ---------------- 128x128 tile GEMM (glls, BK=64) + hist slice (y==16) ------
__global__ __launch_bounds__(256) void gemm128(
    const u16* __restrict__ A, const u16* __restrict__ W,
    const float* __restrict__ bias0, const float* __restrict__ bias1,
    u16* __restrict__ out0, u16* __restrict__ out1,
    int M, int Nout, int K,
    const int* __restrict__ ei, int* __restrict__ deg)
{
  const int tid  = threadIdx.x;
  if (blockIdx.y == 16) {             // fused degree histogram (32 blocks)
#pragma unroll
    for (int i = 0; i < 16; ++i) {
      const int e = blockIdx.x * 4096 + i * 256 + tid;
      atomicAdd(&deg[ei[E_EDGES + e]], 1);
    }
    return;
  }
  const int lane = tid & 63, wave = tid >> 6;
  const int quad = lane >> 4, l16 = lane & 15;
  const int wm = wave >> 1, wn = wave & 1;   // 2x2 wave grid, 64x64 per wave
  const int bm = blockIdx.x, bnb = blockIdx.y;

  __shared__ __align__(16) u16 As[128][64];
  __shared__ __align__(16) u16 Ws[128][64];

  f32x4 acc[4][4] = {};

  const int lr = lane >> 3, gs = lane & 7;
  const int g8 = (gs ^ lr) * 8;
  const u16* ab = A + (size_t)(bm  * 128 + wave * 32 + lr) * K + g8;
  const u16* wb = W + (size_t)(bnb * 128 + wave * 32 + lr) * K + g8;

  for (int k0 = 0; k0 < K; k0 += 64) {
    __syncthreads();
#pragma unroll
    for (int c = 0; c < 4; ++c) {
      glds16(ab + (size_t)(c * 8) * K + k0, &As[wave * 32 + c * 8][0]);
      glds16(wb + (size_t)(c * 8) * K + k0, &Ws[wave * 32 + c * 8][0]);
    }
    __syncthreads();
#pragma unroll
    for (int ks = 0; ks < 2; ++ks) {
      const int slot = ((ks * 4 + quad) ^ (l16 & 7)) * 8;
      bf16x8 af[4], bf[4];
#pragma unroll
      for (int am = 0; am < 4; ++am)
        af[am] = *(const bf16x8*)&As[wm * 64 + am * 16 + l16][slot];
#pragma unroll
      for (int bn = 0; bn < 4; ++bn)
        bf[bn] = *(const bf16x8*)&Ws[wn * 64 + bn * 16 + l16][slot];
#pragma unroll
      for (int am = 0; am < 4; ++am)
#pragma unroll
        for (int bn = 0; bn < 4; ++bn)
          acc[am][bn] = __builtin_amdgcn_mfma_f32_16x16x32_bf16(af[am], bf[bn], acc[am][bn], 0, 0, 0);
    }
  }

#pragma unroll
  for (int am = 0; am < 4; ++am)
#pragma unroll
    for (int bn = 0; bn < 4; ++bn) {
      const int col = bnb * 128 + wn * 64 + bn * 16 + l16;
      const float bias_v = (col < 512) ? bias0[col] : bias1[col - 512];
#pragma unroll
      for (int r = 0; r < 4; ++r) {
        const int row = bm * 128 + wm * 64 + am * 16 + quad * 4 + r;
        float v = acc[am][bn][r] + bias_v;
        if (col < 512) out0[(size_t)row * 512 + col] = f2b(v);
        else           out1[(size_t)row * 1536 + (col - 512)] = f2b(v);
      }
    }
}

// ---------------- scan (bx==512) + V transpose (bx<512), one dispatch -------
__global__ __launch_bounds__(256) void scan_vtrans(
    const int* __restrict__ deg, int* __restrict__ off, int* __restrict__ cursor,
    const u16* __restrict__ qkv, u16* __restrict__ vt)
{
  if (blockIdx.x == 512) {            // exclusive scan of 4096 degrees
    __shared__ int part[256];
    const int t = threadIdx.x;
    int v[16];
    int s = 0;
#pragma unroll
    for (int i = 0; i < 16; ++i) { v[i] = deg[t * 16 + i]; s += v[i]; }
    part[t] = s;
    __syncthreads();
    for (int d = 1; d < 256; d <<= 1) {
      int val = (t >= d) ? part[t - d] : 0;
      __syncthreads();
      if (t >= d) part[t] += val;
      __syncthreads();
    }
    int prefix = (t == 0) ? 0 : part[t - 1];
#pragma unroll
    for (int i = 0; i < 16; ++i) {
      off[t * 16 + i] = prefix;
      cursor[t * 16 + i] = prefix;
      prefix += v[i];
    }
    if (t == 255) off[4096] = prefix;
    return;
  }
  // vtrans: vt[h][d][m] = V[m][h][d], one 64m x 64d head-tile per block
  __shared__ __align__(16) u16 T[64][64];
  const int tid = threadIdx.x;
  const int h = blockIdx.x >> 6, mt = blockIdx.x & 63;
  const int m0 = mt * 64;
  const int c  = tid & 7;            // d-chunk (8 u16 = 16B)
  const int mr = tid >> 3;           // 0..31
#pragma unroll
  for (int half = 0; half < 2; ++half) {
    const int m = mr + half * 32;
    const u16x8 v = *(const u16x8*)(qkv + (size_t)(m0 + m) * 1536 + 1024 + h * 64 + c * 8);
    // store element (m,d) at column-chunk (d>>3) ^ (m>>3): bank-clean both ways
    *(u16x8*)&T[m][((c ^ (m >> 3)) * 8)] = v;
  }
  __syncthreads();
#pragma unroll
  for (int half = 0; half < 2; ++half) {
    const int q = tid + half * 256;
    const int d = q >> 3, mc = q & 7;
    u16x8 w;
#pragma unroll
    for (int e = 0; e < 8; ++e)
      w[e] = T[mc * 8 + e][(((d >> 3) ^ mc) * 8) + (d & 7)];
    *(u16x8*)(vt + (size_t)(h * 64 + d) * N_NODES + m0 + mc * 8) = w;
  }
}

// ---------------- flash attention (+ fill slice at z==SPLITS) ---------------
// Swapped QK^T + in-register P (R14); head=XCD mapping (R16); single-barrier
// dbuf (R20); lsum via ones-MFMA (R21). R23: SPLITS=5 -> 5 blocks/CU
// (32KB LDS x 5 = 160KB exactly); split ranges via (split*64)/SPLITS.
template<int SPLITS>
__global__ __launch_bounds__(256) void attn_kernel(
    const u16* __restrict__ qkv, const u16* __restrict__ vt,
    u16* __restrict__ opart, float* __restrict__ lpart,
    const int* __restrict__ ei, int* __restrict__ cursor, int* __restrict__ csr)
{
  const int tid = threadIdx.x, wave = tid >> 6, lane = tid & 63;
  const int split = blockIdx.z;
  if (split == SPLITS) {              // fused CSR fill (256 blocks, 2 edges/thr)
    const int sblk = blockIdx.y * 32 + blockIdx.x;
#pragma unroll
    for (int i = 0; i < 2; ++i) {
      const int e = sblk * 512 + i * 256 + tid;
      const int s = ei[e];
      const int d = ei[E_EDGES + e];
      const int p = atomicAdd(&cursor[d], 1);
      csr[p] = s;
    }
    return;
  }
  const int quad = lane >> 4, l16 = lane & 15;
  // head = linear_block_id % 8 (= XCD on MI355X round-robin dispatch)
  const int h = blockIdx.x & 7;
  const int tile = (blockIdx.x >> 3) + (blockIdx.y << 2);

  __shared__ __align__(16) u16 Ks[2][64][64];    // K tiles, XOR-swizzled, dbuf
  __shared__ __align__(16) u16 Vts[2][64][64];   // V^T tiles, XOR-swizzled, dbuf

  const float QSCALE = 0.18033688011112042f;  // log2(e)/8
  bf16x8 aq[2][2];   // Q[l16][quad*8..+7]: B-operand for K*Q^T
#pragma unroll
  for (int mb = 0; mb < 2; ++mb) {
    const int qrow = tile * 128 + wave * 32 + mb * 16 + l16;
    const u16* qp = qkv + (size_t)qrow * 1536 + h * 64 + quad * 8;
    u16x8 q0 = *(const u16x8*)qp;
    u16x8 q1 = *(const u16x8*)(qp + 32);
    u16x8 s0, s1;
#pragma unroll
    for (int i = 0; i < 8; ++i) {
      s0[i] = f2b(b2f(q0[i]) * QSCALE);
      s1[i] = f2b(b2f(q1[i]) * QSCALE);
    }
    aq[mb][0] = __builtin_bit_cast(bf16x8, s0);
    aq[mb][1] = __builtin_bit_cast(bf16x8, s1);
  }

  // all-ones B-fragment for P*1 row-sums on the matrix pipe
  u16x8 ones_u;
#pragma unroll
  for (int i = 0; i < 8; ++i) ones_u[i] = 0x3F80;
  const bf16x8 vone = __builtin_bit_cast(bf16x8, ones_u);

  f32x4 O[2][4] = {};
  f32x4 lacc[2] = {};   // D[q][*] = sum_k P[q][k] (cols identical)

  const int lr = lane >> 3, gs = lane & 7;
  const int g8 = (gs ^ lr) * 8;
  const int R0 = wave * 16 + lr;

  const u16* kp = qkv + (size_t)R0 * 1536 + 512 + h * 64 + g8;
  const u16* vp = vt + (size_t)(h * 64 + R0) * N_NODES + g8;

  const int mt0 = (split * 64) / SPLITS, mt1 = ((split + 1) * 64) / SPLITS;

  {   // prologue: stage first tile into buffer 0
    const size_t ko = (size_t)mt0 * 64 * 1536;
    glds16(kp + ko,            &Ks[0][wave * 16][0]);
    glds16(kp + ko + 8 * 1536, &Ks[0][wave * 16 + 8][0]);
    glds16(vp + mt0 * 64,               &Vts[0][wave * 16][0]);
    glds16(vp + mt0 * 64 + 8 * N_NODES, &Vts[0][wave * 16 + 8][0]);
  }

  for (int mt = mt0; mt < mt1; ++mt) {
    const int cur = (mt - mt0) & 1;
    // my stage(t) loads landed (issued after the previous barrier, they had a
    // full compute phase to complete)
    asm volatile("s_waitcnt vmcnt(0)" ::: "memory");
    __builtin_amdgcn_s_barrier();     // all waves' stage(t) landed; buf^1 free
    __builtin_amdgcn_sched_barrier(0);
    if (mt + 1 < mt1) {               // restage buf^1; lands during compute
      const size_t ko = (size_t)(mt + 1) * 64 * 1536;
      glds16(kp + ko,            &Ks[cur ^ 1][wave * 16][0]);
      glds16(kp + ko + 8 * 1536, &Ks[cur ^ 1][wave * 16 + 8][0]);
      glds16(vp + (mt + 1) * 64,               &Vts[cur ^ 1][wave * 16][0]);
      glds16(vp + (mt + 1) * 64 + 8 * N_NODES, &Vts[cur ^ 1][wave * 16 + 8][0]);
    }

    // S^T = K (cQ)^T : D[row=m_local][col=q]
    f32x4 st[2][4] = {};
    __builtin_amdgcn_s_setprio(1);
#pragma unroll
    for (int ks = 0; ks < 2; ++ks) {
      const int slot = ((ks * 4 + quad) ^ (l16 & 7)) * 8;
      bf16x8 af[4];
#pragma unroll
      for (int jn = 0; jn < 4; ++jn)
        af[jn] = *(const bf16x8*)&Ks[cur][jn * 16 + l16][slot];
#pragma unroll
      for (int mb = 0; mb < 2; ++mb)
#pragma unroll
        for (int jn = 0; jn < 4; ++jn)
          st[mb][jn] = __builtin_amdgcn_mfma_f32_16x16x32_bf16(af[jn], aq[mb][ks], st[mb][jn], 0, 0, 0);
    }
    __builtin_amdgcn_s_setprio(0);

    // p = exp2(st): lane (q=l16, quad) holds P[q][m = jn*16 + quad*4 + r].
    // Pack pairs, then 2-stage swap butterfly -> PV A-frag (R14 mapping):
    //   A[ks][c]@quad t  <-  pk[jn][i]@quad qs,
    //   ks=jn>>1, c=2*(qs&1)+i, t=2*(jn&1)+(qs>>1)   (bijective)
    bf16x8 pa[2][2];
#pragma unroll
    for (int mb = 0; mb < 2; ++mb) {
      u32 pk[4][2];
#pragma unroll
      for (int jn = 0; jn < 4; ++jn) {
        float p0 = __builtin_amdgcn_exp2f(st[mb][jn][0]);
        float p1 = __builtin_amdgcn_exp2f(st[mb][jn][1]);
        float p2 = __builtin_amdgcn_exp2f(st[mb][jn][2]);
        float p3 = __builtin_amdgcn_exp2f(st[mb][jn][3]);
        pk[jn][0] = cvtpk(p0, p1);
        pk[jn][1] = cvtpk(p2, p3);
      }
#pragma unroll
      for (int ks = 0; ks < 2; ++ks) {
        u32 x0 = pk[2 * ks][0], y0 = pk[2 * ks + 1][0];
        u32 x1 = pk[2 * ks][1], y1 = pk[2 * ks + 1][1];
        pl32swap(x0, y0); pl16swap(x0, y0);
        pl32swap(x1, y1); pl16swap(x1, y1);
        u32x4 av;
        av[0] = x0; av[1] = x1; av[2] = y0; av[3] = y1;
        pa[mb][ks] = __builtin_bit_cast(bf16x8, av);
      }
    }

    // O += P V ; lacc += P * 1 (row-sum on the matrix pipe)
    __builtin_amdgcn_s_setprio(1);
#pragma unroll
    for (int ks = 0; ks < 2; ++ks) {
      const int slot = ((ks * 4 + quad) ^ (l16 & 7)) * 8;
      bf16x8 bv[4];
#pragma unroll
      for (int jd = 0; jd < 4; ++jd)
        bv[jd] = *(const bf16x8*)&Vts[cur][jd * 16 + l16][slot];
#pragma unroll
      for (int mb = 0; mb < 2; ++mb) {
#pragma unroll
        for (int jd = 0; jd < 4; ++jd)
          O[mb][jd] = __builtin_amdgcn_mfma_f32_16x16x32_bf16(pa[mb][ks], bv[jd], O[mb][jd], 0, 0, 0);
        lacc[mb] = __builtin_amdgcn_mfma_f32_16x16x32_bf16(pa[mb][ks], vone, lacc[mb], 0, 0, 0);
      }
    }
    __builtin_amdgcn_s_setprio(0);
    // no bottom barrier: next iteration's vmcnt(0)+barrier covers both hazards
  }

  // write unnormalized partials (bf16) + row sums (lacc cols identical)
#pragma unroll
  for (int mb = 0; mb < 2; ++mb) {
#pragma unroll
    for (int r = 0; r < 4; ++r) {
      const int row = tile * 128 + wave * 32 + mb * 16 + quad * 4 + r;
      u16* orow = opart + ((size_t)split * N_NODES + row) * C_DIM + h * 64;
#pragma unroll
      for (int jd = 0; jd < 4; ++jd)
        orow[jd * 16 + l16] = f2b(O[mb][jd][r]);
      if (l16 == 0)
        lpart[((size_t)split * N_NODES + row) * H_HEADS + h] = lacc[mb][r];
    }
  }
}

// ---------------- combine (y==1) + gather-mean (y==0), one dispatch ---------
template<int SPLITS>
__global__ __launch_bounds__(256) void combine_gather(
    const u16* __restrict__ opart, const float* __restrict__ lpart,
    u16* __restrict__ ctx,
    const int* __restrict__ off, const int* __restrict__ csr,
    const u16* __restrict__ lh, float* __restrict__ lo)
{
  if (blockIdx.y == 0) {              // gather: one wave per dst node
    const int wave = threadIdx.x >> 6, lane = threadIdx.x & 63;
    const int n = blockIdx.x * 4 + wave;
    const int j0 = off[n], j1 = off[n + 1];
    float acc[8] = {};
    int j = j0;
    // 4-deep software pipeline: 4 independent row loads in flight
    for (; j + 4 <= j1; j += 4) {
      const int s0 = csr[j], s1 = csr[j + 1], s2 = csr[j + 2], s3 = csr[j + 3];
      const u16x8 v0 = *(const u16x8*)(lh + (size_t)s0 * C_DIM + lane * 8);
      const u16x8 v1 = *(const u16x8*)(lh + (size_t)s1 * C_DIM + lane * 8);
      const u16x8 v2 = *(const u16x8*)(lh + (size_t)s2 * C_DIM + lane * 8);
      const u16x8 v3 = *(const u16x8*)(lh + (size_t)s3 * C_DIM + lane * 8);
#pragma unroll
      for (int i = 0; i < 8; ++i)
        acc[i] += (b2f(v0[i]) + b2f(v1[i])) + (b2f(v2[i]) + b2f(v3[i]));
    }
    for (; j < j1; ++j) {
      const int s = csr[j];
      const u16x8 v = *(const u16x8*)(lh + (size_t)s * C_DIM + lane * 8);
#pragma unroll
      for (int i = 0; i < 8; ++i) acc[i] += b2f(v[i]);
    }
    const float inv = 1.0f / fmaxf((float)(j1 - j0), 1.0f);
    f32x4 o0, o1;
#pragma unroll
    for (int i = 0; i < 4; ++i) { o0[i] = acc[i] * inv; o1[i] = acc[4 + i] * inv; }
    float* op = lo + (size_t)n * C_DIM + lane * 8;
    *(f32x4*)op = o0;
    *(f32x4*)(op + 4) = o1;
    return;
  }
  // combine split partials
  const size_t base = (size_t)(blockIdx.x * 256 + threadIdx.x) * 8;
  const int row = (int)(base >> 9);
  const int h = (int)((base & 511) >> 6);
  float l = 0.0f;
#pragma unroll
  for (int s = 0; s < SPLITS; ++s)
    l += lpart[(size_t)s * N_NODES * H_HEADS + (size_t)row * H_HEADS + h];
  const float inv = 1.0f / l;
  float o[8] = {};
#pragma unroll
  for (int s = 0; s < SPLITS; ++s) {
    const u16x8 p = *(const u16x8*)(opart + (size_t)s * N_NODES * C_DIM + base);
#pragma unroll
    for (int i = 0; i < 8; ++i) o[i] += b2f(p[i]);
  }
  u16x8 ob;
#pragma unroll
  for (int i = 0; i < 8; ++i) ob[i] = f2b(o[i] * inv);
  *(u16x8*)(ctx + base) = ob;
}

// ---------------- LayerNorms (one wave per row) ----------------
__global__ __launch_bounds__(256) void ln1_kernel(
    const float* __restrict__ x, const float* __restrict__ pr,
    const float* __restrict__ g, const float* __restrict__ b,
    u16* __restrict__ hb, float* __restrict__ hf)
{
  const int wave = threadIdx.x >> 6, lane = threadIdx.x & 63;
  const int row = blockIdx.x * 4 + wave;
  const int c0 = lane * 8;
  const size_t base = (size_t)row * C_DIM + c0;
  f32x4 x0 = *(const f32x4*)(x + base);
  f32x4 x1 = *(const f32x4*)(x + base + 4);
  f32x4 p0 = *(const f32x4*)(pr + base);
  f32x4 p1 = *(const f32x4*)(pr + base + 4);
  float v[8];
#pragma unroll
  for (int i = 0; i < 4; ++i) { v[i] = x0[i] + p0[i]; v[4 + i] = x1[i] + p1[i]; }
  float sum = 0, sq = 0;
#pragma unroll
  for (int i = 0; i < 8; ++i) { sum += v[i]; sq += v[i] * v[i]; }
  for (int off = 1; off < 64; off <<= 1) { sum += __shfl_xor(sum, off); sq += __shfl_xor(sq, off); }
  const float mean = sum * (1.0f / C_DIM);
  const float var  = sq * (1.0f / C_DIM) - mean * mean;
  const float rstd = rsqrtf(var + 1e-5f);
  f32x4 g0 = *(const f32x4*)(g + c0), g1 = *(const f32x4*)(g + c0 + 4);
  f32x4 b0 = *(const f32x4*)(b + c0), b1 = *(const f32x4*)(b + c0 + 4);
  u16x8 ob; f32x4 h0, h1;
#pragma unroll
  for (int i = 0; i < 4; ++i) {
    float hv0 = (v[i]     - mean) * rstd * g0[i] + b0[i];
    float hv1 = (v[4 + i] - mean) * rstd * g1[i] + b1[i];
    h0[i] = hv0; h1[i] = hv1;
    ob[i] = f2b(hv0); ob[4 + i] = f2b(hv1);
  }
  *(u16x8*)(hb + base) = ob;
  *(f32x4*)(hf + base) = h0;
  *(f32x4*)(hf + base + 4) = h1;
}

__global__ __launch_bounds__(256) void ln2_kernel(
    const float* __restrict__ a, const float* __restrict__ c,
    const float* __restrict__ g, const float* __restrict__ b,
    float* __restrict__ out)
{
  const int wave = threadIdx.x >> 6, lane = threadIdx.x & 63;
  const int row = blockIdx.x * 4 + wave;
  const int c0 = lane * 8;
  const size_t base = (size_t)row * C_DIM + c0;
  f32x4 a0 = *(const f32x4*)(a + base), a1 = *(const f32x4*)(a + base + 4);
  f32x4 c0v = *(const f32x4*)(c + base), c1v = *(const f32x4*)(c + base + 4);
  float v[8];
#pragma unroll
  for (int i = 0; i < 4; ++i) { v[i] = a0[i] + c0v[i]; v[4 + i] = a1[i] + c1v[i]; }
  float sum = 0, sq = 0;
#pragma unroll
  for (int i = 0; i < 8; ++i) { sum += v[i]; sq += v[i] * v[i]; }
  for (int off = 1; off < 64; off <<= 1) { sum += __shfl_xor(sum, off); sq += __shfl_xor(sq, off); }
  const float mean = sum * (1.0f / C_DIM);
  const float var  = sq * (1.0f / C_DIM) - mean * mean;
  const float rstd = rsqrtf(var + 1e-5f);
  f32x4 g0 = *(const f32x4*)(g + c0), g1 = *(const f32x4*)(g + c0 + 4);
  f32x4 b0 = *(const f32x4*)(b + c0), b1 = *(const f32x4*)(b + c0 + 4);
  f32x4 h0, h1;
#pragma unroll
  for (int i = 0; i < 4; ++i) {
    h0[i] = (v[i]     - mean) * rstd * g0[i] + b0[i];
    h1[i] = (v[4 + i] - mean) * rstd * g1[i] + b1[i];
  }
  *(f32x4*)(out + base) = h0;
  *(f32x4*)(out + base + 4) = h1;
}

// ---------------- launch ----------------
extern "C" void kernel_launch(void* const* d_in, const int* in_sizes, int n_in,
                              void* d_out, int out_size, void* d_ws, size_t ws_size,
                              hipStream_t stream) {
  const float* x          = (const float*)d_in[0];
  const int*   ei         = (const int*)d_in[1];
  const float* local_w    = (const float*)d_in[2];
  const float* local_b    = (const float*)d_in[3];
  const float* in_proj_w  = (const float*)d_in[4];
  const float* in_proj_b  = (const float*)d_in[5];
  const float* attn_out_w = (const float*)d_in[6];
  const float* attn_out_b = (const float*)d_in[7];
  const float* output_w   = (const float*)d_in[8];
  const float* output_b   = (const float*)d_in[9];
  const float* n1g = (const float*)d_in[10];
  const float* n1b = (const float*)d_in[11];
  const float* n2g = (const float*)d_in[12];
  const float* n2b = (const float*)d_in[13];
  const float* ffn_w1 = (const float*)d_in[14];
  const float* ffn_b1 = (const float*)d_in[15];
  const float* ffn_w2 = (const float*)d_in[16];
  const float* ffn_b2 = (const float*)d_in[17];
  float* out = (float*)d_out;

  char* ws = (char*)d_ws;
  size_t o = 0;
  float* local_out = (float*)(ws + o); o += (size_t)N_NODES * C_DIM * 4;  // 8 MB
  int* deg    = (int*)(ws + o); o += (N_NODES) * 4;
  int* off    = (int*)(ws + o); o += (N_NODES + 16) * 4;
  int* cursor = (int*)(ws + o); o += (N_NODES) * 4;
  int* csr    = (int*)(ws + o); o += (size_t)E_EDGES * 4;
  u16* xb   = (u16*)(ws + o); o += (size_t)N_NODES * C_DIM * 2;           // 4 MB
  u16* wbLQ = (u16*)(ws + o); o += (size_t)4 * C_DIM * C_DIM * 2;         // 2 MB
  u16* wbA  = (u16*)(ws + o); o += (size_t)C_DIM * C_DIM * 2;
  u16* wbO  = (u16*)(ws + o); o += (size_t)C_DIM * C_DIM * 2;
  u16* wbF1 = (u16*)(ws + o); o += (size_t)2 * C_DIM * C_DIM * 2;
  u16* wbF2 = (u16*)(ws + o); o += (size_t)2 * C_DIM * C_DIM * 2;
  u16* local_h   = (u16*)(ws + o); o += (size_t)N_NODES * C_DIM * 2;
  u16* qkvb      = (u16*)(ws + o); o += (size_t)N_NODES * 3 * C_DIM * 2;  // 12 MB
  u16* ctxb      = (u16*)(ws + o); o += (size_t)N_NODES * C_DIM * 2;
  u16* mixed     = (u16*)(ws + o); o += (size_t)N_NODES * C_DIM * 2;
  u16* hidden_bf = (u16*)(ws + o); o += (size_t)N_NODES * C_DIM * 2;      // 4 MB
  float* hidden_f = (float*)(ws + o); o += (size_t)N_NODES * C_DIM * 4;   // 8 MB
  u16* ff1       = (u16*)(ws + o); o += (size_t)N_NODES * 2 * C_DIM * 2;  // 8 MB
  // aliases (dead ranges reused):
  float* proj  = (float*)qkvb;       // qkv dead after attn; proj 8 MB <= 12 MB
  float* ff2   = (float*)local_out;  // local_out dead after mix-epilogue gemm
  u16*   vt    = xb;                 // xb dead after LQKV gemm; 4 MB
  // split partials past static region (bf16 opart + f32 lpart)
  u16* opartN = (u16*)(ws + o);
  const size_t need5 = o + (size_t)5 * N_NODES * C_DIM * 2 + (size_t)5 * N_NODES * H_HEADS * 4;
  const size_t need4 = o + (size_t)4 * N_NODES * C_DIM * 2 + (size_t)4 * N_NODES * H_HEADS * 4;
  float* lpart5 = (float*)(ws + o + (size_t)5 * N_NODES * C_DIM * 2);
  float* lpart4 = (float*)(ws + o + (size_t)4 * N_NODES * C_DIM * 2);
  const bool use5 = (ws_size >= need5);
  const bool use4 = (ws_size >= need4);
  // SPLITS=2 fallback: inside hidden_bf..ff1 region (8.25 MB <= 20 MB)
  u16* opart2 = (u16*)hidden_bf;
  float* lpart2 = (float*)(opart2 + (size_t)2 * N_NODES * C_DIM);

  // D1: fp32 -> bf16 conversions + deg zeroing (slice t==7)
  CvtArgs ca;
  ca.src[0] = x;          ca.dst[0] = xb;   ca.n[0] = N_NODES * C_DIM;
  ca.src[1] = local_w;    ca.dst[1] = wbLQ;                  ca.n[1] = C_DIM * C_DIM;
  ca.src[2] = in_proj_w;  ca.dst[2] = wbLQ + C_DIM * C_DIM;  ca.n[2] = 3 * C_DIM * C_DIM;
  ca.src[3] = attn_out_w; ca.dst[3] = wbA;  ca.n[3] = C_DIM * C_DIM;
  ca.src[4] = output_w;   ca.dst[4] = wbO;  ca.n[4] = C_DIM * C_DIM;
  ca.src[5] = ffn_w1;     ca.dst[5] = wbF1; ca.n[5] = 2 * C_DIM * C_DIM;
  ca.src[6] = ffn_w2;     ca.dst[6] = wbF2; ca.n[6] = 2 * C_DIM * C_DIM;
  ca.deg = deg;
  cvt_multi<<<dim3(N_NODES * C_DIM / 2048, 8), 256, 0, stream>>>(ca);

  // D2: merged local+qkv GEMM + degree histogram (y==16)
  gemm128<<<dim3(32, 17), 256, 0, stream>>>(xb, wbLQ, local_b, in_proj_b,
      local_h, qkvb, N_NODES, 4 * C_DIM, C_DIM, ei, deg);

  // D3: scan (bx==512) + V transpose (bx<512); xb dead after D2
  scan_vtrans<<<513, 256, 0, stream>>>(deg, off, cursor, qkvb, vt);

  // D4: attention + CSR fill (z==SPLITS); D5: combine + gather
  if (use5) {
    attn_kernel<5><<<dim3(32, 8, 6), 256, 0, stream>>>(qkvb, vt, opartN, lpart5,
        ei, cursor, csr);
    combine_gather<5><<<dim3(1024, 2), 256, 0, stream>>>(opartN, lpart5, ctxb,
        off, csr, local_h, local_out);
  } else if (use4) {
    attn_kernel<4><<<dim3(32, 8, 5), 256, 0, stream>>>(qkvb, vt, opartN, lpart4,
        ei, cursor, csr);
    combine_gather<4><<<dim3(1024, 2), 256, 0, stream>>>(opartN, lpart4, ctxb,
        off, csr, local_h, local_out);
  } else {
    attn_kernel<2><<<dim3(32, 8, 3), 256, 0, stream>>>(qkvb, vt, opart2, lpart2,
        ei, cursor, csr);
    combine_gather<2><<<dim3(1024, 2), 256, 0, stream>>>(opart2, lpart2, ctxb,
        off, csr, local_h, local_out);
  }

  // D6: mixed = 0.5*local_out + 0.5*(ctx @ attn_out_w^T + b)
  gemm_bt<3><<<dim3(64, 8), 256, 0, stream>>>(ctxb, wbA, attn_out_b, mixed,
      N_NODES, C_DIM, C_DIM, local_out);

  // D7: proj = mixed @ output_w^T + b ; D8: hidden = LN(x + proj)
  gemm_bt<1><<<dim3(64, 8), 256, 0, stream>>>(mixed, wbO, output_b, proj,
      N_NODES, C_DIM, C_DIM, nullptr);
  ln1_kernel<<<N_NODES / 4, 256, 0, stream>>>(x, proj, n1g, n1b, hidden_bf, hidden_f);

  // D9-D11: FFN + LN2
  gemm_bt<2><<<dim3(64, 16), 256, 0, stream>>>(hidden_bf, wbF1, ffn_b1, ff1,
      N_NODES, 2 * C_DIM, C_DIM, nullptr);
  gemm_bt<1><<<dim3(64, 8), 256, 0, stream>>>(ff1, wbF2, ffn_b2, ff2,
      N_NODES, C_DIM, 2 * C_DIM, nullptr);
  ln2_kernel<<<N_NODES / 4, 256, 0, stream>>>(hidden_f, ff2, n2g, n2b, out);
}